// Round 8
// baseline (133.104 us; speedup 1.0000x reference)
//
#include <hip/hip_runtime.h>
#include <hip/hip_bf16.h>

// SnakeBrain fused kernel, round 8: fully independent tiles via double commute.
// R7 post-mortem: 3 structurally different kernels all ~31-35us -> stall-bound
// on the serial cross-tile chain (stencil2(t) needs tile t+1's MFMA -> rolling
// window of MFMA+bpermute latency, uncoverable at 4 waves/SIMD, grid = one
// generation). Fix: S(r1@W2) = (S r1)@W2 -- stencil-2 applied to r1 BEFORE the
// GEMM, neighbor r1 RECOMPUTED from x (2 fma/ch) instead of shfl'd. Interior
// 1/3 folded into B (W2/3). Deletes accP/accN, all stencil-2 bpermutes,
// sender-role selects, edge masks; main loop has ZERO DS ops and no cross-tile
// deps. Head verbatim from validated R6. One wave = one snake, no barriers.

#define NB  4096
#define CL  256
#define HID 32
#define FIN 64

typedef __attribute__((ext_vector_type(8))) short    bf16x8;
typedef __attribute__((ext_vector_type(4))) float    f32x4;
typedef __attribute__((ext_vector_type(2))) float    f32x2;
typedef __attribute__((ext_vector_type(4))) unsigned u32x4;

__device__ __forceinline__ unsigned pkbf(float a, float b) {
    // bf16(a) low 16, bf16(b) high 16 (RNE, v_cvt_pk_bf16_f32)
    __hip_bfloat162 hb = __float22bfloat162_rn(make_float2(a, b));
    unsigned u; __builtin_memcpy(&u, &hb, sizeof(u));
    return u;
}
__device__ __forceinline__ float bflo(unsigned u) { return __builtin_bit_cast(float, u << 16); }
__device__ __forceinline__ float bfhi(unsigned u) { return __builtin_bit_cast(float, u & 0xffff0000u); }

__device__ __forceinline__ f32x2 sfma(float s, f32x2 v, f32x2 a) {
    f32x2 sv = {s, s};
    return __builtin_elementwise_fma(sv, v, a);
}
__device__ __forceinline__ f32x2 smul(float s, f32x2 v) { f32x2 sv = {s, s}; return sv * v; }
__device__ __forceinline__ f32x2 vmax0(f32x2 v) {
    f32x2 z = {0.f, 0.f};
    return __builtin_elementwise_max(v, z);
}

// GCN chain coefficients for node n (deg incl self-loop: 3 interior, 2 ends)
__device__ __forceinline__ void gcn_coef(int n, float& nc, float& nl, float& nr) {
    const float IS3 = 0.57735026918962576f, IS2 = 0.70710678118654752f;
    const float dn = (n == 0 || n == CL - 1) ? IS2 : IS3;
    nc = dn * dn;
    nl = (n > 0)      ? dn * ((n == 1)      ? IS2 : IS3) : 0.0f;
    nr = (n < CL - 1) ? dn * ((n == CL - 2) ? IS2 : IS3) : 0.0f;
}

__global__ __launch_bounds__(256, 4) void snake_fused(
    const float* __restrict__ x,
    const float* __restrict__ heads,
    const float* __restrict__ body_sizes,
    const float* __restrict__ fruits,
    const float* __restrict__ W1, const float* __restrict__ b1,
    const float* __restrict__ W2, const float* __restrict__ b2,
    const float* __restrict__ Wr, const float* __restrict__ br,
    const float* __restrict__ Wa1, const float* __restrict__ ba1,
    const float* __restrict__ Wa2, const float* __restrict__ ba2,
    const float* __restrict__ Wc, const float* __restrict__ bc,
    const float* __restrict__ Wp, const float* __restrict__ bp,
    const float* __restrict__ Wv, const float* __restrict__ bv,
    float* __restrict__ out)
{
    __shared__ __align__(16) float wsc[4][FIN];   // per-wave scratch, no barriers

    const int tid  = threadIdx.x;
    const int w    = tid >> 6;
    const int lane = tid & 63;
    const int g    = lane >> 4;     // A k-group
    const int c    = lane & 15;     // tile row (node within tile) / C col
    const int gs   = blockIdx.x * 4 + w;   // this wave's snake

    const float THIRD = 0.33333333333333333f;

    // ---- B fragments: split-bf16 of W2 * (1/3) (interior stencil-2 folded) ----
    // B layout: B[k=8g+j][n=c+16nt]
    bf16x8 Bh[2], Bl[2];
    #pragma unroll
    for (int nt = 0; nt < 2; ++nt) {
        unsigned hh[4], ll[4];
        #pragma unroll
        for (int p = 0; p < 4; ++p) {
            const float wa = W2[(8 * g + 2 * p)     * HID + c + 16 * nt] * THIRD;
            const float wb = W2[(8 * g + 2 * p + 1) * HID + c + 16 * nt] * THIRD;
            const unsigned hu = pkbf(wa, wb);
            hh[p] = hu;
            ll[p] = pkbf(wa - bflo(hu), wb - bfhi(hu));
        }
        u32x4 H = {hh[0], hh[1], hh[2], hh[3]};
        u32x4 L = {ll[0], ll[1], ll[2], ll[3]};
        Bh[nt] = __builtin_bit_cast(bf16x8, H);
        Bl[nt] = __builtin_bit_cast(bf16x8, L);
    }
    const float b2v0 = b2[c], b2v1 = b2[c + 16];

    // W1/b1 channel-pair slices for this lane's A-channels 8g..8g+7
    const float4 W1a0 = *(const float4*)(W1 + 8 * g);
    const float4 W1a1 = *(const float4*)(W1 + 8 * g + 4);
    const float4 W1b0 = *(const float4*)(W1 + HID + 8 * g);
    const float4 W1b1 = *(const float4*)(W1 + HID + 8 * g + 4);
    const float4 b1v0 = *(const float4*)(b1 + 8 * g);
    const float4 b1v1 = *(const float4*)(b1 + 8 * g + 4);
    const f32x2 W1ap[4] = {{W1a0.x, W1a0.y}, {W1a0.z, W1a0.w}, {W1a1.x, W1a1.y}, {W1a1.z, W1a1.w}};
    const f32x2 W1bp[4] = {{W1b0.x, W1b0.y}, {W1b0.z, W1b0.w}, {W1b1.x, W1b1.y}, {W1b1.z, W1b1.w}};
    const f32x2 b1p[4]  = {{b1v0.x, b1v0.y}, {b1v0.z, b1v0.w}, {b1v1.x, b1v1.y}, {b1v1.z, b1v1.w}};

    const float2* xs = (const float2*)x + gs * CL;

    float sum0 = 0.f, sum1 = 0.f;   // pool partial for cols c / c+16

    // r1 pair at one node: relu(Sx.x * W1a + Sx.y * W1b + b1)
    auto r1p = [&](const f32x2 Sx, int p) -> f32x2 {
        return vmax0(sfma(Sx.x, W1ap[p], sfma(Sx.y, W1bp[p], b1p[p])));
    };

    #pragma unroll
    for (int t = 0; t < 16; ++t) {
        const int m = 16 * t + c;               // this lane's node for tile t
        int im2 = m - 2, im1 = m - 1, ip1 = m + 1, ip2 = m + 2;
        if (t == 0)  { im2 = im2 < 0 ? 0 : im2;  im1 = im1 < 0 ? 0 : im1; }
        if (t == 15) { ip1 = ip1 > CL - 1 ? CL - 1 : ip1;  ip2 = ip2 > CL - 1 ? CL - 1 : ip2; }
        const float2 v0 = xs[im2], v1 = xs[im1], v2 = xs[m], v3 = xs[ip1], v4 = xs[ip2];
        const f32x2 x0 = {v0.x, v0.y}, x1 = {v1.x, v1.y}, x2 = {v2.x, v2.y};
        const f32x2 x3 = {v3.x, v3.y}, x4 = {v4.x, v4.y};

        // stencil-1 (true coefs) at nodes m-1, m, m+1
        f32x2 SxL, SxC, SxR;
        if (t == 0 || t == 15) {
            float aC, aL, aR;
            gcn_coef(im1, aC, aL, aR);
            SxL = sfma(aC, x1, sfma(aL, x0, smul(aR, x2)));
            gcn_coef(m, aC, aL, aR);
            SxC = sfma(aC, x2, sfma(aL, x1, smul(aR, x3)));
            gcn_coef(ip1, aC, aL, aR);
            SxR = sfma(aC, x3, sfma(aL, x2, smul(aR, x4)));
        } else {
            SxL = smul(THIRD, (x0 + x1) + x2);
            SxC = smul(THIRD, (x1 + x2) + x3);
            SxR = smul(THIRD, (x2 + x3) + x4);
        }

        // stencil-2 weights (x3, since 1/3 folded into B); interior = raw sum
        float cC2 = 1.f, cL2 = 1.f, cR2 = 1.f;
        if (t == 0 || t == 15) {
            gcn_coef(m, cC2, cL2, cR2);
            cC2 *= 3.f; cL2 *= 3.f; cR2 *= 3.f;
        }

        // Sh = weighted sum of recomputed r1 at m-1, m, m+1; split to bf16 hi/lo
        unsigned HH[4], LL[4];
        #pragma unroll
        for (int p = 0; p < 4; ++p) {
            const f32x2 rL = r1p(SxL, p);
            const f32x2 rC = r1p(SxC, p);
            const f32x2 rR = r1p(SxR, p);
            f32x2 Sh;
            if (t == 0 || t == 15)
                Sh = sfma(cL2, rL, sfma(cC2, rC, smul(cR2, rR)));
            else
                Sh = (rL + rC) + rR;
            const unsigned h = pkbf(Sh.x, Sh.y);
            const f32x2 hf = {bflo(h), bfhi(h)};
            const f32x2 lo = Sh - hf;
            HH[p] = h;
            LL[p] = pkbf(lo.x, lo.y);
        }
        u32x4 HU = {HH[0], HH[1], HH[2], HH[3]};
        u32x4 LU = {LL[0], LL[1], LL[2], LL[3]};
        const bf16x8 ah = __builtin_bit_cast(bf16x8, HU);
        const bf16x8 al = __builtin_bit_cast(bf16x8, LU);

        // GEMM tile (3-term split) + bias + relu + pool, no cross-tile deps
        #pragma unroll
        for (int nt = 0; nt < 2; ++nt) {
            f32x4 a0 = {0.f, 0.f, 0.f, 0.f};
            a0 = __builtin_amdgcn_mfma_f32_16x16x32_bf16(ah, Bh[nt], a0, 0, 0, 0);
            a0 = __builtin_amdgcn_mfma_f32_16x16x32_bf16(al, Bh[nt], a0, 0, 0, 0);
            a0 = __builtin_amdgcn_mfma_f32_16x16x32_bf16(ah, Bl[nt], a0, 0, 0, 0);
            const float bb = nt ? b2v1 : b2v0;
            const f32x2 bv2 = {bb, bb};
            f32x2 q01 = {a0[0], a0[1]}, q23 = {a0[2], a0[3]};
            q01 = vmax0(q01 + bv2);
            q23 = vmax0(q23 + bv2);
            const f32x2 qs = q01 + q23;
            const float hs = qs.x + qs.y;
            if (nt == 0) sum0 += hs; else sum1 += hs;
        }
    }

    // ---- mean pool: butterfly over the 4 row-groups (bits 4,5) ----
    sum0 += __shfl_xor(sum0, 16, 64); sum0 += __shfl_xor(sum0, 32, 64);
    sum1 += __shfl_xor(sum1, 16, 64); sum1 += __shfl_xor(sum1, 32, 64);
    wsc[w][c]      = sum0 * (1.0f / CL);   // convergent (4 lanes, same value)
    wsc[w][c + 16] = sum1 * (1.0f / CL);

    // ---- head (R6 verbatim: per wave, own snake, in-order same-wave DS) ----
    if (lane >= 32) {     // aux1 in lanes 32-63
        const int cc = lane - 32;
        float a = ba1[cc];
        a = fmaf(heads[2 * gs],      Wa1[0 * HID + cc], a);
        a = fmaf(heads[2 * gs + 1],  Wa1[1 * HID + cc], a);
        a = fmaf(body_sizes[gs],     Wa1[2 * HID + cc], a);
        a = fmaf(fruits[2 * gs],     Wa1[3 * HID + cc], a);
        a = fmaf(fruits[2 * gs + 1], Wa1[4 * HID + cc], a);
        wsc[w][32 + cc] = fmaxf(a, 0.f);
    }
    // merged convergent stage: lanes 0-31 body_emb (no relu), 32-63 aux2 (relu)
    {
        const int  hh = lane >> 5;
        const int  cc = lane & 31;
        const float* Wsel = hh ? Wa2 : Wr;
        const float  bsel = hh ? ba2[cc] : br[cc];
        const float* lsel = &wsc[w][32 * hh];
        float cv = bsel;
        #pragma unroll
        for (int k4 = 0; k4 < 8; ++k4) {
            const f32x4 p = *(const f32x4*)&lsel[4 * k4];   // broadcast b128
            cv = fmaf(p[0], Wsel[(4 * k4 + 0) * HID + cc], cv);
            cv = fmaf(p[1], Wsel[(4 * k4 + 1) * HID + cc], cv);
            cv = fmaf(p[2], Wsel[(4 * k4 + 2) * HID + cc], cv);
            cv = fmaf(p[3], Wsel[(4 * k4 + 3) * HID + cc], cv);
        }
        cv = hh ? fmaxf(cv, 0.f) : cv;
        wsc[w][lane] = cv;    // cat; same-wave in-order DS
    }
    // combined = relu(cat @ Wc + bc), then logits/value butterfly
    {
        float cb = bc[lane];
        #pragma unroll
        for (int k4 = 0; k4 < 16; ++k4) {
            const f32x4 p = *(const f32x4*)&wsc[w][4 * k4];
            cb = fmaf(p[0], Wc[(4 * k4 + 0) * FIN + lane], cb);
            cb = fmaf(p[1], Wc[(4 * k4 + 1) * FIN + lane], cb);
            cb = fmaf(p[2], Wc[(4 * k4 + 2) * FIN + lane], cb);
            cb = fmaf(p[3], Wc[(4 * k4 + 3) * FIN + lane], cb);
        }
        cb = fmaxf(cb, 0.f);
        float s0 = cb * Wp[lane * 5 + 0];
        float s1 = cb * Wp[lane * 5 + 1];
        float s2 = cb * Wp[lane * 5 + 2];
        float s3 = cb * Wp[lane * 5 + 3];
        float s4 = cb * Wp[lane * 5 + 4];
        float s5 = cb * Wv[lane];
        #pragma unroll
        for (int m = 1; m <= 32; m <<= 1) {
            s0 += __shfl_xor(s0, m, 64);
            s1 += __shfl_xor(s1, m, 64);
            s2 += __shfl_xor(s2, m, 64);
            s3 += __shfl_xor(s3, m, 64);
            s4 += __shfl_xor(s4, m, 64);
            s5 += __shfl_xor(s5, m, 64);
        }
        if (lane == 0) {
            out[gs * 5 + 0] = s0 + bp[0];
            out[gs * 5 + 1] = s1 + bp[1];
            out[gs * 5 + 2] = s2 + bp[2];
            out[gs * 5 + 3] = s3 + bp[3];
            out[gs * 5 + 4] = s4 + bp[4];
            out[NB * 5 + gs] = s5 + bv[0];
        }
    }
}

extern "C" void kernel_launch(void* const* d_in, const int* in_sizes, int n_in,
                              void* d_out, int out_size, void* d_ws, size_t ws_size,
                              hipStream_t stream) {
    const float* x          = (const float*)d_in[0];
    const float* heads      = (const float*)d_in[1];
    const float* body_sizes = (const float*)d_in[2];
    const float* fruits     = (const float*)d_in[3];
    const float* W1 = (const float*)d_in[4];
    const float* b1 = (const float*)d_in[5];
    const float* W2 = (const float*)d_in[6];
    const float* b2 = (const float*)d_in[7];
    const float* Wr = (const float*)d_in[8];
    const float* br = (const float*)d_in[9];
    const float* Wa1 = (const float*)d_in[10];
    const float* ba1 = (const float*)d_in[11];
    const float* Wa2 = (const float*)d_in[12];
    const float* ba2 = (const float*)d_in[13];
    const float* Wc = (const float*)d_in[14];
    const float* bc = (const float*)d_in[15];
    const float* Wp = (const float*)d_in[16];
    const float* bp = (const float*)d_in[17];
    const float* Wv = (const float*)d_in[18];
    const float* bv = (const float*)d_in[19];

    float* out = (float*)d_out;
    snake_fused<<<NB / 4, 256, 0, stream>>>(
        x, heads, body_sizes, fruits,
        W1, b1, W2, b2, Wr, br, Wa1, ba1, Wa2, ba2,
        Wc, bc, Wp, bp, Wv, bv, out);
}

// Round 9
// 128.632 us; speedup vs baseline: 1.0348x; 1.0348x over previous
//
#include <hip/hip_runtime.h>
#include <hip/hip_bf16.h>

// SnakeBrain fused kernel, round 9: zero-VMEM main loop.
// R8 post-mortem: 4 structural rewrites (DS, barriers, VALU slots, serial
// deps) all ~flat -> remaining shared cost is cold-memory latency: harness
// poisons 268MB d_ws before EVERY replay, evicting L2 AND L3, so per-tile x
// loads are HBM-cold (~900cyc). Fix: prefetch whole snake (2KB) via 2
// coalesced dwordx4/lane at kernel start (overlaps B-build latency), stash in
// per-wave LDS, feed stencils from ds_read_b64 (conflict-free). Main loop has
// ZERO VMEM. Tiles 0/15 peeled; interior branch-free; unroll 2 (no spills).
// Structure otherwise = validated R8: one wave = one snake, no barriers,
// stencil-2 commuted before GEMM (interior 1/3 folded into B), split-bf16 MFMA.

#define NB  4096
#define CL  256
#define HID 32
#define FIN 64

typedef __attribute__((ext_vector_type(8))) short    bf16x8;
typedef __attribute__((ext_vector_type(4))) float    f32x4;
typedef __attribute__((ext_vector_type(2))) float    f32x2;
typedef __attribute__((ext_vector_type(4))) unsigned u32x4;

__device__ __forceinline__ unsigned pkbf(float a, float b) {
    // bf16(a) low 16, bf16(b) high 16 (RNE, v_cvt_pk_bf16_f32)
    __hip_bfloat162 hb = __float22bfloat162_rn(make_float2(a, b));
    unsigned u; __builtin_memcpy(&u, &hb, sizeof(u));
    return u;
}
__device__ __forceinline__ float bflo(unsigned u) { return __builtin_bit_cast(float, u << 16); }
__device__ __forceinline__ float bfhi(unsigned u) { return __builtin_bit_cast(float, u & 0xffff0000u); }

__device__ __forceinline__ f32x2 sfma(float s, f32x2 v, f32x2 a) {
    f32x2 sv = {s, s};
    return __builtin_elementwise_fma(sv, v, a);
}
__device__ __forceinline__ f32x2 smul(float s, f32x2 v) { f32x2 sv = {s, s}; return sv * v; }
__device__ __forceinline__ f32x2 vmax0(f32x2 v) {
    f32x2 z = {0.f, 0.f};
    return __builtin_elementwise_max(v, z);
}

// GCN chain coefficients for node n (deg incl self-loop: 3 interior, 2 ends)
__device__ __forceinline__ void gcn_coef(int n, float& nc, float& nl, float& nr) {
    const float IS3 = 0.57735026918962576f, IS2 = 0.70710678118654752f;
    const float dn = (n == 0 || n == CL - 1) ? IS2 : IS3;
    nc = dn * dn;
    nl = (n > 0)      ? dn * ((n == 1)      ? IS2 : IS3) : 0.0f;
    nr = (n < CL - 1) ? dn * ((n == CL - 2) ? IS2 : IS3) : 0.0f;
}

__global__ __launch_bounds__(256, 4) void snake_fused(
    const float* __restrict__ x,
    const float* __restrict__ heads,
    const float* __restrict__ body_sizes,
    const float* __restrict__ fruits,
    const float* __restrict__ W1, const float* __restrict__ b1,
    const float* __restrict__ W2, const float* __restrict__ b2,
    const float* __restrict__ Wr, const float* __restrict__ br,
    const float* __restrict__ Wa1, const float* __restrict__ ba1,
    const float* __restrict__ Wa2, const float* __restrict__ ba2,
    const float* __restrict__ Wc, const float* __restrict__ bc,
    const float* __restrict__ Wp, const float* __restrict__ bp,
    const float* __restrict__ Wv, const float* __restrict__ bv,
    float* __restrict__ out)
{
    __shared__ __align__(16) float2 xsh[4][CL];   // 8 KB: per-wave snake x
    __shared__ __align__(16) float  wsc[4][FIN];  // 1 KB: per-wave head scratch

    const int tid  = threadIdx.x;
    const int w    = tid >> 6;
    const int lane = tid & 63;
    const int g    = lane >> 4;     // A k-group
    const int c    = lane & 15;     // node within tile / C col
    const int gs   = blockIdx.x * 4 + w;   // this wave's snake

    const float THIRD = 0.33333333333333333f;

    // ---- x prefetch: whole snake (2 KB) in 2 coalesced dwordx4 per lane ----
    const float4* xg4 = (const float4*)(x + gs * 2 * CL);
    const float4 f0 = xg4[lane];
    const float4 f1 = xg4[lane + 64];

    // ---- B fragments: split-bf16 of W2 * (1/3) (interior stencil-2 folded) ----
    // B layout: B[k=8g+j][n=c+16nt]
    bf16x8 Bh[2], Bl[2];
    #pragma unroll
    for (int nt = 0; nt < 2; ++nt) {
        unsigned hh[4], ll[4];
        #pragma unroll
        for (int p = 0; p < 4; ++p) {
            const float wa = W2[(8 * g + 2 * p)     * HID + c + 16 * nt] * THIRD;
            const float wb = W2[(8 * g + 2 * p + 1) * HID + c + 16 * nt] * THIRD;
            const unsigned hu = pkbf(wa, wb);
            hh[p] = hu;
            ll[p] = pkbf(wa - bflo(hu), wb - bfhi(hu));
        }
        u32x4 H = {hh[0], hh[1], hh[2], hh[3]};
        u32x4 L = {ll[0], ll[1], ll[2], ll[3]};
        Bh[nt] = __builtin_bit_cast(bf16x8, H);
        Bl[nt] = __builtin_bit_cast(bf16x8, L);
    }
    const float b2v0 = b2[c], b2v1 = b2[c + 16];

    // W1/b1 channel-pair slices for this lane's A-channels 8g..8g+7
    const float4 W1a0 = *(const float4*)(W1 + 8 * g);
    const float4 W1a1 = *(const float4*)(W1 + 8 * g + 4);
    const float4 W1b0 = *(const float4*)(W1 + HID + 8 * g);
    const float4 W1b1 = *(const float4*)(W1 + HID + 8 * g + 4);
    const float4 b1v0 = *(const float4*)(b1 + 8 * g);
    const float4 b1v1 = *(const float4*)(b1 + 8 * g + 4);
    const f32x2 W1ap[4] = {{W1a0.x, W1a0.y}, {W1a0.z, W1a0.w}, {W1a1.x, W1a1.y}, {W1a1.z, W1a1.w}};
    const f32x2 W1bp[4] = {{W1b0.x, W1b0.y}, {W1b0.z, W1b0.w}, {W1b1.x, W1b1.y}, {W1b1.z, W1b1.w}};
    const f32x2 b1p[4]  = {{b1v0.x, b1v0.y}, {b1v0.z, b1v0.w}, {b1v1.x, b1v1.y}, {b1v1.z, b1v1.w}};

    // ---- stash x to per-wave LDS (same-wave in-order DS: no barrier) ----
    {
        float4* sh4 = (float4*)&xsh[w][0];
        sh4[lane]      = f0;
        sh4[lane + 64] = f1;
    }

    float sum0 = 0.f, sum1 = 0.f;   // pool partials for cols c / c+16

    // r1 pair at one node: relu(Sx.x * W1a + Sx.y * W1b + b1)
    auto r1p = [&](const f32x2 Sx, int p) -> f32x2 {
        return vmax0(sfma(Sx.x, W1ap[p], sfma(Sx.y, W1bp[p], b1p[p])));
    };
    auto ldx = [&](int idx) -> f32x2 {
        const float2 v = xsh[w][idx];       // ds_read_b64, conflict-free
        f32x2 r = {v.x, v.y};
        return r;
    };

    // One GEMM m-tile: nodes 16t..16t+15. All inputs from LDS; no cross-tile
    // deps. `edge` is compile-time at each call site.
    auto do_tile = [&](int t, bool edge) {
        const int m = 16 * t + c;
        int im2 = m - 2, im1 = m - 1, ip1 = m + 1, ip2 = m + 2;
        if (edge) {
            im2 = im2 < 0 ? 0 : im2;  im1 = im1 < 0 ? 0 : im1;
            ip1 = ip1 > CL - 1 ? CL - 1 : ip1;  ip2 = ip2 > CL - 1 ? CL - 1 : ip2;
        }
        const f32x2 x0 = ldx(im2), x1 = ldx(im1), x2 = ldx(m);
        const f32x2 x3 = ldx(ip1), x4 = ldx(ip2);

        f32x2 SxL, SxC, SxR;
        float cC2 = 1.f, cL2 = 1.f, cR2 = 1.f;
        if (edge) {
            float aC, aL, aR;
            gcn_coef(im1, aC, aL, aR);
            SxL = sfma(aC, x1, sfma(aL, x0, smul(aR, x2)));
            gcn_coef(m, aC, aL, aR);
            SxC = sfma(aC, x2, sfma(aL, x1, smul(aR, x3)));
            gcn_coef(ip1, aC, aL, aR);
            SxR = sfma(aC, x3, sfma(aL, x2, smul(aR, x4)));
            gcn_coef(m, cC2, cL2, cR2);
            cC2 *= 3.f; cL2 *= 3.f; cR2 *= 3.f;
        } else {
            SxL = smul(THIRD, (x0 + x1) + x2);
            SxC = smul(THIRD, (x1 + x2) + x3);
            SxR = smul(THIRD, (x2 + x3) + x4);
        }

        // Sh = stencil-2-weighted sum of r1 at m-1,m,m+1; split to bf16 hi/lo
        unsigned HH[4], LL[4];
        #pragma unroll
        for (int p = 0; p < 4; ++p) {
            const f32x2 rL = r1p(SxL, p);
            const f32x2 rC = r1p(SxC, p);
            const f32x2 rR = r1p(SxR, p);
            f32x2 Sh;
            if (edge)
                Sh = sfma(cL2, rL, sfma(cC2, rC, smul(cR2, rR)));
            else
                Sh = (rL + rC) + rR;
            const unsigned h = pkbf(Sh.x, Sh.y);
            const f32x2 hf = {bflo(h), bfhi(h)};
            const f32x2 lo = Sh - hf;
            HH[p] = h;
            LL[p] = pkbf(lo.x, lo.y);
        }
        u32x4 HU = {HH[0], HH[1], HH[2], HH[3]};
        u32x4 LU = {LL[0], LL[1], LL[2], LL[3]};
        const bf16x8 ah = __builtin_bit_cast(bf16x8, HU);
        const bf16x8 al = __builtin_bit_cast(bf16x8, LU);

        // 3-term split GEMM tile + bias + relu + pool
        #pragma unroll
        for (int nt = 0; nt < 2; ++nt) {
            f32x4 a0 = {0.f, 0.f, 0.f, 0.f};
            a0 = __builtin_amdgcn_mfma_f32_16x16x32_bf16(ah, Bh[nt], a0, 0, 0, 0);
            a0 = __builtin_amdgcn_mfma_f32_16x16x32_bf16(al, Bh[nt], a0, 0, 0, 0);
            a0 = __builtin_amdgcn_mfma_f32_16x16x32_bf16(ah, Bl[nt], a0, 0, 0, 0);
            const float bb = nt ? b2v1 : b2v0;
            const f32x2 bv2 = {bb, bb};
            f32x2 q01 = {a0[0], a0[1]}, q23 = {a0[2], a0[3]};
            q01 = vmax0(q01 + bv2);
            q23 = vmax0(q23 + bv2);
            const f32x2 qs = q01 + q23;
            const float hs = qs.x + qs.y;
            if (nt == 0) sum0 += hs; else sum1 += hs;
        }
    };

    do_tile(0, true);
    #pragma unroll 2
    for (int t = 1; t < 15; ++t) do_tile(t, false);
    do_tile(15, true);

    // ---- mean pool: butterfly over the 4 row-groups (bits 4,5) ----
    sum0 += __shfl_xor(sum0, 16, 64); sum0 += __shfl_xor(sum0, 32, 64);
    sum1 += __shfl_xor(sum1, 16, 64); sum1 += __shfl_xor(sum1, 32, 64);
    wsc[w][c]      = sum0 * (1.0f / CL);   // convergent (4 lanes, same value)
    wsc[w][c + 16] = sum1 * (1.0f / CL);

    // ---- head (validated R6/R8: per wave, own snake, in-order same-wave DS) ----
    if (lane >= 32) {     // aux1 in lanes 32-63
        const int cc = lane - 32;
        float a = ba1[cc];
        a = fmaf(heads[2 * gs],      Wa1[0 * HID + cc], a);
        a = fmaf(heads[2 * gs + 1],  Wa1[1 * HID + cc], a);
        a = fmaf(body_sizes[gs],     Wa1[2 * HID + cc], a);
        a = fmaf(fruits[2 * gs],     Wa1[3 * HID + cc], a);
        a = fmaf(fruits[2 * gs + 1], Wa1[4 * HID + cc], a);
        wsc[w][32 + cc] = fmaxf(a, 0.f);
    }
    // merged convergent stage: lanes 0-31 body_emb (no relu), 32-63 aux2 (relu)
    {
        const int  hh = lane >> 5;
        const int  cc = lane & 31;
        const float* Wsel = hh ? Wa2 : Wr;
        const float  bsel = hh ? ba2[cc] : br[cc];
        const float* lsel = &wsc[w][32 * hh];
        float cv = bsel;
        #pragma unroll
        for (int k4 = 0; k4 < 8; ++k4) {
            const f32x4 p = *(const f32x4*)&lsel[4 * k4];   // broadcast b128
            cv = fmaf(p[0], Wsel[(4 * k4 + 0) * HID + cc], cv);
            cv = fmaf(p[1], Wsel[(4 * k4 + 1) * HID + cc], cv);
            cv = fmaf(p[2], Wsel[(4 * k4 + 2) * HID + cc], cv);
            cv = fmaf(p[3], Wsel[(4 * k4 + 3) * HID + cc], cv);
        }
        cv = hh ? fmaxf(cv, 0.f) : cv;
        wsc[w][lane] = cv;    // cat; same-wave in-order DS
    }
    // combined = relu(cat @ Wc + bc), then logits/value butterfly
    {
        float cb = bc[lane];
        #pragma unroll
        for (int k4 = 0; k4 < 16; ++k4) {
            const f32x4 p = *(const f32x4*)&wsc[w][4 * k4];
            cb = fmaf(p[0], Wc[(4 * k4 + 0) * FIN + lane], cb);
            cb = fmaf(p[1], Wc[(4 * k4 + 1) * FIN + lane], cb);
            cb = fmaf(p[2], Wc[(4 * k4 + 2) * FIN + lane], cb);
            cb = fmaf(p[3], Wc[(4 * k4 + 3) * FIN + lane], cb);
        }
        cb = fmaxf(cb, 0.f);
        float s0 = cb * Wp[lane * 5 + 0];
        float s1 = cb * Wp[lane * 5 + 1];
        float s2 = cb * Wp[lane * 5 + 2];
        float s3 = cb * Wp[lane * 5 + 3];
        float s4 = cb * Wp[lane * 5 + 4];
        float s5 = cb * Wv[lane];
        #pragma unroll
        for (int m = 1; m <= 32; m <<= 1) {
            s0 += __shfl_xor(s0, m, 64);
            s1 += __shfl_xor(s1, m, 64);
            s2 += __shfl_xor(s2, m, 64);
            s3 += __shfl_xor(s3, m, 64);
            s4 += __shfl_xor(s4, m, 64);
            s5 += __shfl_xor(s5, m, 64);
        }
        if (lane == 0) {
            out[gs * 5 + 0] = s0 + bp[0];
            out[gs * 5 + 1] = s1 + bp[1];
            out[gs * 5 + 2] = s2 + bp[2];
            out[gs * 5 + 3] = s3 + bp[3];
            out[gs * 5 + 4] = s4 + bp[4];
            out[NB * 5 + gs] = s5 + bv[0];
        }
    }
}

extern "C" void kernel_launch(void* const* d_in, const int* in_sizes, int n_in,
                              void* d_out, int out_size, void* d_ws, size_t ws_size,
                              hipStream_t stream) {
    const float* x          = (const float*)d_in[0];
    const float* heads      = (const float*)d_in[1];
    const float* body_sizes = (const float*)d_in[2];
    const float* fruits     = (const float*)d_in[3];
    const float* W1 = (const float*)d_in[4];
    const float* b1 = (const float*)d_in[5];
    const float* W2 = (const float*)d_in[6];
    const float* b2 = (const float*)d_in[7];
    const float* Wr = (const float*)d_in[8];
    const float* br = (const float*)d_in[9];
    const float* Wa1 = (const float*)d_in[10];
    const float* ba1 = (const float*)d_in[11];
    const float* Wa2 = (const float*)d_in[12];
    const float* ba2 = (const float*)d_in[13];
    const float* Wc = (const float*)d_in[14];
    const float* bc = (const float*)d_in[15];
    const float* Wp = (const float*)d_in[16];
    const float* bp = (const float*)d_in[17];
    const float* Wv = (const float*)d_in[18];
    const float* bv = (const float*)d_in[19];

    float* out = (float*)d_out;
    snake_fused<<<NB / 4, 256, 0, stream>>>(
        x, heads, body_sizes, fruits,
        W1, b1, W2, b2, Wr, br, Wa1, ba1, Wa2, ba2,
        Wc, bc, Wp, bp, Wv, bv, out);
}